// Round 2
// baseline (255.759 us; speedup 1.0000x reference)
//
#include <hip/hip_runtime.h>
#include <hip/hip_bf16.h>

#define B_   64
#define P_   8732
#define C_   81
#define M_   20
#define BP_  (B_*P_)
#define CEB  128
#define SBLK 1024

// ---------------- Kernel 1: IoU + threshold truth + per-gt best-prior candidates ----------------
__global__ __launch_bounds__(256) void iou_kernel(
    const float* __restrict__ priors, const float* __restrict__ tboxes,
    int* __restrict__ truth, unsigned long long* __restrict__ bestkey)
{
    const int b = blockIdx.y;
    const int tid = threadIdx.x;
    __shared__ float s_gt[M_][4];
    __shared__ float s_ga[M_];
    __shared__ float s_red[M_][4];
    __shared__ int   s_redp[M_][4];

    if (tid < M_*4) ((float*)s_gt)[tid] = tboxes[b*M_*4 + tid];
    __syncthreads();
    if (tid < M_) s_ga[tid] = (s_gt[tid][2]-s_gt[tid][0]) * (s_gt[tid][3]-s_gt[tid][1]);
    __syncthreads();

    float lb[M_]; int lp[M_];
    #pragma unroll
    for (int m=0;m<M_;++m){ lb[m] = -1.0f; lp[m] = 0x7FFFFFFF; }

    const float4* pr4 = (const float4*)priors;
    const int p0 = blockIdx.x * 1024;
    const int pend = min(p0 + 1024, P_);
    for (int p = p0 + tid; p < pend; p += 256) {
        float4 pc = pr4[p];
        float px0 = pc.x - pc.z*0.5f, py0 = pc.y - pc.w*0.5f;
        float px1 = pc.x + pc.z*0.5f, py1 = pc.y + pc.w*0.5f;
        float pa = pc.z * pc.w;
        float best = -1.0f; int bg = 0;
        #pragma unroll
        for (int m=0;m<M_;++m){
            float ix0 = fmaxf(s_gt[m][0], px0);
            float iy0 = fmaxf(s_gt[m][1], py0);
            float ix1 = fminf(s_gt[m][2], px1);
            float iy1 = fminf(s_gt[m][3], py1);
            float iw = fmaxf(ix1-ix0, 0.f), ih = fmaxf(iy1-iy0, 0.f);
            float inter = iw*ih;
            float iou = inter / (s_ga[m] + pa - inter + 1e-10f);
            if (iou > best) { best = iou; bg = m; }   // first-max tie rule (ascending m)
            if (iou > lb[m]) { lb[m] = iou; lp[m] = p; }  // ascending p: ties keep first
        }
        truth[(size_t)b*P_ + p] = (best >= 0.5f) ? bg : -1;
    }

    const int lane = tid & 63, wid = tid >> 6;
    #pragma unroll
    for (int m=0;m<M_;++m){
        float v = lb[m]; int ip = lp[m];
        for (int off=32; off; off>>=1){
            float ov = __shfl_down(v, off); int op = __shfl_down(ip, off);
            if (ov > v || (ov == v && op < ip)) { v = ov; ip = op; }
        }
        if (lane == 0) { s_red[m][wid] = v; s_redp[m][wid] = ip; }
    }
    __syncthreads();
    if (tid < M_) {
        const int m = tid;
        float v = s_red[m][0]; int ip = s_redp[m][0];
        for (int w=1; w<4; ++w){
            float ov = s_red[m][w]; int op = s_redp[m][w];
            if (ov > v || (ov == v && op < ip)) { v = ov; ip = op; }
        }
        // v >= 0 guaranteed (block covers >=1 prior, iou >= 0)
        unsigned long long key = ((unsigned long long)__float_as_uint(v) << 32)
                               | (unsigned)(P_ - 1 - ip);   // ties -> smaller p wins
        atomicMax(&bestkey[b*M_ + m], key);
    }
}

// ---------------- Kernel 2: forced-match override (numpy scatter, last-wins) ----------------
__global__ void override_kernel(const unsigned long long* __restrict__ bestkey,
                                int* __restrict__ truth)
{
    const int b = threadIdx.x;
    if (b >= B_) return;
    int* trow = truth + (size_t)b * P_;
    for (int m = 0; m < M_; ++m) {   // ascending m: last write wins
        unsigned long long key = bestkey[b*M_ + m];
        int p = P_ - 1 - (int)(unsigned)(key & 0xFFFFFFFFu);
        trow[p] = m;
    }
}

// ---------------- Kernel 3: encode + smooth-L1 + target class + pos count ----------------
__global__ __launch_bounds__(256) void loc_kernel(
    const float* __restrict__ pred_loc, const float* __restrict__ priors,
    const float* __restrict__ tboxes, const int* __restrict__ tlabels,
    const int* __restrict__ truth, int* __restrict__ tclass,
    float* __restrict__ loc_sum, int* __restrict__ pos_cnt)
{
    const int tid = threadIdx.x;
    float acc = 0.f;
    const int base = blockIdx.x * 1024;
    const int end = min(base + 1024, BP_);
    for (int i = base + tid; i < end; i += 256) {
        const int t = truth[i];
        int cls = 0;
        if (t >= 0) {
            const int b = i / P_;
            const int p = i - b * P_;
            cls = tlabels[b*M_ + t];
            float4 pc = ((const float4*)priors)[p];
            float4 g  = ((const float4*)tboxes)[b*M_ + t];
            float gcx = (g.x+g.z)*0.5f, gcy = (g.y+g.w)*0.5f;
            float gw = g.z - g.x, gh = g.w - g.y;
            float e0 = (gcx - pc.x) / (pc.z * 0.1f);
            float e1 = (gcy - pc.y) / (pc.w * 0.1f);
            float e2 = __logf(gw / pc.z + 1e-5f) * 5.0f;
            float e3 = __logf(gh / pc.w + 1e-5f) * 5.0f;
            float4 pl = ((const float4*)pred_loc)[i];
            float d0 = pl.x-e0, d1 = pl.y-e1, d2 = pl.z-e2, d3 = pl.w-e3;
            float a0 = fabsf(d0), a1 = fabsf(d1), a2 = fabsf(d2), a3 = fabsf(d3);
            acc += (a0<1.f ? 0.5f*d0*d0 : a0-0.5f)
                 + (a1<1.f ? 0.5f*d1*d1 : a1-0.5f)
                 + (a2<1.f ? 0.5f*d2*d2 : a2-0.5f)
                 + (a3<1.f ? 0.5f*d3*d3 : a3-0.5f);
            atomicAdd(&pos_cnt[b], 1);
        }
        tclass[i] = cls;
    }
    __shared__ float s_w[4];
    for (int off=32; off; off>>=1) acc += __shfl_down(acc, off);
    if ((tid & 63) == 0) s_w[tid>>6] = acc;
    __syncthreads();
    if (tid == 0) atomicAdd(loc_sum, s_w[0]+s_w[1]+s_w[2]+s_w[3]);
}

// ---------------- Kernel 4: cross-entropy per prior (memory-dominant) ----------------
__global__ __launch_bounds__(256) void ce_kernel(
    const float* __restrict__ pred_conf, const int* __restrict__ tclass,
    float* __restrict__ ce_out)
{
    __shared__ float sc[CEB * C_];
    const size_t base = (size_t)blockIdx.x * CEB;
    const float4* src = (const float4*)(pred_conf + base * C_);
    float4* dst = (float4*)sc;
    const int NV = CEB * C_ / 4;   // 2592
    for (int i = threadIdx.x; i < NV; i += 256) dst[i] = src[i];
    __syncthreads();

    const int lp   = threadIdx.x >> 1;
    const int half = threadIdx.x & 1;
    const float* row = &sc[lp * C_];
    const int c0 = half * 41;
    const int cn = 41 - half;      // 41 or 40
    float mx = -1e30f;
    for (int c = 0; c < cn; ++c) mx = fmaxf(mx, row[c0 + c]);
    mx = fmaxf(mx, __shfl_xor(mx, 1));
    float s = 0.f;
    for (int c = 0; c < cn; ++c) s += __expf(row[c0 + c] - mx);
    s += __shfl_xor(s, 1);
    const size_t bp = base + lp;
    const int t = tclass[bp];
    if (half == 0) ce_out[bp] = mx + __logf(s) - row[t];
}

// ---------------- Kernel 5: per-row radix-select top-k hard negatives (LDS-resident) ----------------
__global__ __launch_bounds__(SBLK) void select_kernel(
    const float* __restrict__ ce, const int* __restrict__ tclass,
    const int* __restrict__ pos_cnt, float* __restrict__ conf_sum,
    float* __restrict__ mask_cnt)
{
    const int b = blockIdx.x; const int tid = threadIdx.x;
    const int lane = tid & 63, wid = tid >> 6;
    __shared__ float sm[P_];
    __shared__ unsigned hist[256];
    __shared__ unsigned s_prefix, s_remk, s_cntgt;
    __shared__ float s_r1[SBLK/64], s_r2[SBLK/64];

    const float* cerow = ce + (size_t)b * P_;
    const int*   tcrow = tclass + (size_t)b * P_;
    float sp = 0.f;
    for (int i = tid; i < P_; i += SBLK) {
        float cv = cerow[i];
        int tc = tcrow[i];
        if (tc > 0) { sp += cv; sm[i] = 0.f; }
        else sm[i] = cv;
    }
    const int pos = pos_cnt[b];
    const unsigned k = (unsigned)min(3 * pos, P_ - 1);
    if (tid == 0) { s_prefix = 0u; s_remk = k; s_cntgt = 0u; }
    __syncthreads();

    for (int pass = 3; pass >= 0; --pass) {
        if (tid < 256) hist[tid] = 0u;
        __syncthreads();
        const unsigned prefix = s_prefix;
        const int shift = pass * 8;
        const unsigned pmask = (pass == 3) ? 0u : (0xFFFFFFFFu << (shift + 8));
        for (int i = tid; i < P_; i += SBLK) {
            const unsigned u = __float_as_uint(sm[i]);
            const bool pred = ((u & pmask) == prefix);
            const int bin = (int)((u >> shift) & 0xFFu);
            // wave-aggregated histogram add (values are heavily clustered)
            unsigned long long todo = __ballot(pred);
            while (todo) {
                const int src = (int)__ffsll(todo) - 1;
                const int lead = __shfl(bin, src);
                const unsigned long long mask = __ballot(pred && (bin == lead));
                if (lane == src) atomicAdd(&hist[lead], (unsigned)__popcll(mask));
                todo &= ~mask;
            }
        }
        __syncthreads();
        if (tid == 0) {
            unsigned acc = 0, remk = s_remk; int chosen = 0;
            for (int bin = 255; bin >= 0; --bin) {
                const unsigned c = hist[bin];
                if (acc + c >= remk) { chosen = bin; break; }
                acc += c;
            }
            s_cntgt += acc;
            s_remk = remk - acc;
            s_prefix = prefix | ((unsigned)chosen << shift);
        }
        __syncthreads();
    }

    const unsigned Tbits = s_prefix;
    const float T = __uint_as_float(Tbits);
    const unsigned cnt_gt = s_cntgt;
    const unsigned sel_eq = s_remk;   // = k - cnt_gt (ties at T selected)

    float sgt = 0.f;
    for (int i = tid; i < P_; i += SBLK) {
        const float v = sm[i];
        if (v > T) sgt += v;
    }
    for (int off=32; off; off>>=1) { sgt += __shfl_down(sgt, off); sp += __shfl_down(sp, off); }
    if (lane == 0) { s_r1[wid] = sgt; s_r2[wid] = sp; }
    __syncthreads();
    if (tid == 0) {
        float a = 0.f, c = 0.f;
        for (int w = 0; w < SBLK/64; ++w) { a += s_r1[w]; c += s_r2[w]; }
        float neg_sum, mc;
        if (Tbits != 0u) { neg_sum = a + (float)sel_eq * T; mc = (float)(pos + (int)k); }
        else             { neg_sum = a;                     mc = (float)(pos + (int)cnt_gt); }
        atomicAdd(conf_sum, c + neg_sum);
        atomicAdd(mask_cnt, mc);
    }
}

// ---------------- Kernel 6: finalize ----------------
__global__ void finalize_kernel(const float* __restrict__ accums, float* __restrict__ out)
{
    out[0] = accums[0] / (float)B_;                 // loc_loss
    out[1] = accums[1] / accums[2] / (float)B_;     // conf_loss
}

extern "C" void kernel_launch(void* const* d_in, const int* in_sizes, int n_in,
                              void* d_out, int out_size, void* d_ws, size_t ws_size,
                              hipStream_t stream) {
    (void)in_sizes; (void)n_in; (void)out_size; (void)ws_size;
    const float* pred_loc  = (const float*)d_in[0];
    const float* pred_conf = (const float*)d_in[1];
    const float* priors    = (const float*)d_in[2];
    const float* tboxes    = (const float*)d_in[3];
    const int*   tlabels   = (const int*)d_in[4];
    float* out = (float*)d_out;

    char* ws = (char*)d_ws;
    int*   tclass  = (int*)ws;                               // BP ints
    float* ce      = (float*)(ws + (size_t)BP_ * 4);         // BP floats
    int*   truth   = (int*)(ws + (size_t)BP_ * 8);           // BP ints
    unsigned long long* bestkey = (unsigned long long*)(ws + (size_t)BP_ * 12);  // B*M u64
    int*   pos_cnt = (int*)(ws + (size_t)BP_ * 12 + B_*M_*8);
    float* accums  = (float*)(ws + (size_t)BP_ * 12 + B_*M_*8 + B_*4);  // [loc,conf,maskcnt]

    // zero: bestkey + pos_cnt + accums (contiguous)
    hipMemsetAsync(bestkey, 0, B_*M_*8 + B_*4 + 3*sizeof(float), stream);

    iou_kernel<<<dim3(9, B_), 256, 0, stream>>>(priors, tboxes, truth, bestkey);
    override_kernel<<<1, B_, 0, stream>>>(bestkey, truth);
    loc_kernel<<<(BP_ + 1023) / 1024, 256, 0, stream>>>(pred_loc, priors, tboxes, tlabels,
                                                        truth, tclass, &accums[0], pos_cnt);
    ce_kernel<<<BP_ / CEB, 256, 0, stream>>>(pred_conf, tclass, ce);
    select_kernel<<<B_, SBLK, 0, stream>>>(ce, tclass, pos_cnt, &accums[1], &accums[2]);
    finalize_kernel<<<1, 1, 0, stream>>>(accums, out);
}

// Round 3
// 196.546 us; speedup vs baseline: 1.3013x; 1.3013x over previous
//
#include <hip/hip_runtime.h>
#include <hip/hip_bf16.h>

#define B_   64
#define P_   8732
#define C_   81
#define M_   20
#define BP_  (B_*P_)
#define CEB  128
#define SBLK 1024

// ---------------- Kernel 0: zero the tiny accumulator regions (replaces hipMemsetAsync) ----------------
__global__ void init_kernel(unsigned long long* __restrict__ bestkey, float* __restrict__ accums)
{
    const int tid = threadIdx.x;
    for (int i = tid; i < B_*M_; i += 256) bestkey[i] = 0ull;
    if (tid < 3) accums[tid] = 0.f;
}

// ---------------- Kernel 1: IoU + threshold truth + per-gt best-prior candidates ----------------
__global__ __launch_bounds__(256) void iou_kernel(
    const float* __restrict__ priors, const float* __restrict__ tboxes,
    int* __restrict__ truth, unsigned long long* __restrict__ bestkey)
{
    const int b = blockIdx.y;
    const int tid = threadIdx.x;
    __shared__ float s_gt[M_][4];
    __shared__ float s_ga[M_];
    __shared__ float s_red[M_][4];
    __shared__ int   s_redp[M_][4];

    if (tid < M_*4) ((float*)s_gt)[tid] = tboxes[b*M_*4 + tid];
    __syncthreads();
    if (tid < M_) s_ga[tid] = (s_gt[tid][2]-s_gt[tid][0]) * (s_gt[tid][3]-s_gt[tid][1]);
    __syncthreads();

    float lb[M_]; int lp[M_];
    #pragma unroll
    for (int m=0;m<M_;++m){ lb[m] = -1.0f; lp[m] = 0x7FFFFFFF; }

    const float4* pr4 = (const float4*)priors;
    const int p0 = blockIdx.x * 1024;
    const int pend = min(p0 + 1024, P_);
    for (int p = p0 + tid; p < pend; p += 256) {
        float4 pc = pr4[p];
        float px0 = pc.x - pc.z*0.5f, py0 = pc.y - pc.w*0.5f;
        float px1 = pc.x + pc.z*0.5f, py1 = pc.y + pc.w*0.5f;
        float pa = pc.z * pc.w;
        float best = -1.0f; int bg = 0;
        #pragma unroll
        for (int m=0;m<M_;++m){
            float ix0 = fmaxf(s_gt[m][0], px0);
            float iy0 = fmaxf(s_gt[m][1], py0);
            float ix1 = fminf(s_gt[m][2], px1);
            float iy1 = fminf(s_gt[m][3], py1);
            float iw = fmaxf(ix1-ix0, 0.f), ih = fmaxf(iy1-iy0, 0.f);
            float inter = iw*ih;
            float iou = inter / (s_ga[m] + pa - inter + 1e-10f);
            if (iou > best) { best = iou; bg = m; }   // first-max tie rule (ascending m)
            if (iou > lb[m]) { lb[m] = iou; lp[m] = p; }  // ascending p: ties keep first
        }
        truth[(size_t)b*P_ + p] = (best >= 0.5f) ? bg : -1;
    }

    const int lane = tid & 63, wid = tid >> 6;
    #pragma unroll
    for (int m=0;m<M_;++m){
        float v = lb[m]; int ip = lp[m];
        for (int off=32; off; off>>=1){
            float ov = __shfl_down(v, off); int op = __shfl_down(ip, off);
            if (ov > v || (ov == v && op < ip)) { v = ov; ip = op; }
        }
        if (lane == 0) { s_red[m][wid] = v; s_redp[m][wid] = ip; }
    }
    __syncthreads();
    if (tid < M_) {
        const int m = tid;
        float v = s_red[m][0]; int ip = s_redp[m][0];
        for (int w=1; w<4; ++w){
            float ov = s_red[m][w]; int op = s_redp[m][w];
            if (ov > v || (ov == v && op < ip)) { v = ov; ip = op; }
        }
        unsigned long long key = ((unsigned long long)__float_as_uint(v) << 32)
                               | (unsigned)(P_ - 1 - ip);   // ties -> smaller p wins
        atomicMax(&bestkey[b*M_ + m], key);
    }
}

// ---------------- Kernel 2: forced-match override (numpy scatter, last-wins) ----------------
__global__ void override_kernel(const unsigned long long* __restrict__ bestkey,
                                int* __restrict__ truth)
{
    const int b = threadIdx.x;
    if (b >= B_) return;
    int* trow = truth + (size_t)b * P_;
    for (int m = 0; m < M_; ++m) {   // ascending m: last write wins
        unsigned long long key = bestkey[b*M_ + m];
        int p = P_ - 1 - (int)(unsigned)(key & 0xFFFFFFFFu);
        trow[p] = m;
    }
}

// ---------------- Kernel 3: encode + smooth-L1 + target class ----------------
__global__ __launch_bounds__(256) void loc_kernel(
    const float* __restrict__ pred_loc, const float* __restrict__ priors,
    const float* __restrict__ tboxes, const int* __restrict__ tlabels,
    const int* __restrict__ truth, int* __restrict__ tclass,
    float* __restrict__ loc_sum)
{
    const int tid = threadIdx.x;
    float acc = 0.f;
    const int base = blockIdx.x * 1024;
    const int end = min(base + 1024, BP_);
    for (int i = base + tid; i < end; i += 256) {
        const int t = truth[i];
        int cls = 0;
        if (t >= 0) {
            const int b = i / P_;
            const int p = i - b * P_;
            cls = tlabels[b*M_ + t];
            float4 pc = ((const float4*)priors)[p];
            float4 g  = ((const float4*)tboxes)[b*M_ + t];
            float gcx = (g.x+g.z)*0.5f, gcy = (g.y+g.w)*0.5f;
            float gw = g.z - g.x, gh = g.w - g.y;
            float e0 = (gcx - pc.x) / (pc.z * 0.1f);
            float e1 = (gcy - pc.y) / (pc.w * 0.1f);
            float e2 = __logf(gw / pc.z + 1e-5f) * 5.0f;
            float e3 = __logf(gh / pc.w + 1e-5f) * 5.0f;
            float4 pl = ((const float4*)pred_loc)[i];
            float d0 = pl.x-e0, d1 = pl.y-e1, d2 = pl.z-e2, d3 = pl.w-e3;
            float a0 = fabsf(d0), a1 = fabsf(d1), a2 = fabsf(d2), a3 = fabsf(d3);
            acc += (a0<1.f ? 0.5f*d0*d0 : a0-0.5f)
                 + (a1<1.f ? 0.5f*d1*d1 : a1-0.5f)
                 + (a2<1.f ? 0.5f*d2*d2 : a2-0.5f)
                 + (a3<1.f ? 0.5f*d3*d3 : a3-0.5f);
        }
        tclass[i] = cls;
    }
    __shared__ float s_w[4];
    for (int off=32; off; off>>=1) acc += __shfl_down(acc, off);
    if ((tid & 63) == 0) s_w[tid>>6] = acc;
    __syncthreads();
    if (tid == 0) atomicAdd(loc_sum, s_w[0]+s_w[1]+s_w[2]+s_w[3]);
}

// ---------------- Kernel 4: cross-entropy per prior (memory-dominant) ----------------
__global__ __launch_bounds__(256) void ce_kernel(
    const float* __restrict__ pred_conf, const int* __restrict__ tclass,
    float* __restrict__ ce_out)
{
    __shared__ float sc[CEB * C_];
    const size_t base = (size_t)blockIdx.x * CEB;
    const float4* src = (const float4*)(pred_conf + base * C_);
    float4* dst = (float4*)sc;
    const int NV = CEB * C_ / 4;   // 2592
    for (int i = threadIdx.x; i < NV; i += 256) dst[i] = src[i];
    __syncthreads();

    const int lp   = threadIdx.x >> 1;
    const int half = threadIdx.x & 1;
    const float* row = &sc[lp * C_];
    const int c0 = half * 41;
    const int cn = 41 - half;      // 41 or 40
    float mx = -1e30f;
    for (int c = 0; c < cn; ++c) mx = fmaxf(mx, row[c0 + c]);
    mx = fmaxf(mx, __shfl_xor(mx, 1));
    float s = 0.f;
    for (int c = 0; c < cn; ++c) s += __expf(row[c0 + c] - mx);
    s += __shfl_xor(s, 1);
    const size_t bp = base + lp;
    const int t = tclass[bp];
    if (half == 0) ce_out[bp] = mx + __logf(s) - row[t];
}

// ---------------- Kernel 5: per-row radix-select top-k hard negatives (LDS-resident) ----------------
__global__ __launch_bounds__(SBLK) void select_kernel(
    const float* __restrict__ ce, const int* __restrict__ tclass,
    float* __restrict__ conf_sum, float* __restrict__ mask_cnt)
{
    const int b = blockIdx.x; const int tid = threadIdx.x;
    const int lane = tid & 63, wid = tid >> 6;
    __shared__ float sm[P_];
    __shared__ unsigned hist[256];
    __shared__ unsigned s_prefix, s_remk, s_cntgt, s_pos;
    __shared__ float s_r1[SBLK/64], s_r2[SBLK/64];
    __shared__ int   s_pc[SBLK/64];

    const float* cerow = ce + (size_t)b * P_;
    const int*   tcrow = tclass + (size_t)b * P_;
    float sp = 0.f; int pcnt = 0;
    for (int i = tid; i < P_; i += SBLK) {
        float cv = cerow[i];
        int tc = tcrow[i];
        if (tc > 0) { sp += cv; sm[i] = 0.f; pcnt++; }
        else sm[i] = cv;
    }
    // block-reduce pos count
    for (int off=32; off; off>>=1) pcnt += __shfl_down(pcnt, off);
    if (lane == 0) s_pc[wid] = pcnt;
    __syncthreads();
    if (tid == 0) {
        int p = 0;
        for (int w = 0; w < SBLK/64; ++w) p += s_pc[w];
        s_pos = (unsigned)p;
        s_prefix = 0u; s_remk = (unsigned)min(3 * p, P_ - 1); s_cntgt = 0u;
    }
    __syncthreads();
    const int pos = (int)s_pos;
    const unsigned k = (unsigned)min(3 * pos, P_ - 1);

    for (int pass = 3; pass >= 0; --pass) {
        if (tid < 256) hist[tid] = 0u;
        __syncthreads();
        const unsigned prefix = s_prefix;
        const int shift = pass * 8;
        const unsigned pmask = (pass == 3) ? 0u : (0xFFFFFFFFu << (shift + 8));
        for (int i = tid; i < P_; i += SBLK) {
            const unsigned u = __float_as_uint(sm[i]);
            const bool pred = ((u & pmask) == prefix);
            const int bin = (int)((u >> shift) & 0xFFu);
            // wave-aggregated histogram add (values are heavily clustered)
            unsigned long long todo = __ballot(pred);
            while (todo) {
                const int src = (int)__ffsll(todo) - 1;
                const int lead = __shfl(bin, src);
                const unsigned long long mask = __ballot(pred && (bin == lead));
                if (lane == src) atomicAdd(&hist[lead], (unsigned)__popcll(mask));
                todo &= ~mask;
            }
        }
        __syncthreads();
        if (tid == 0) {
            unsigned acc = 0, remk = s_remk; int chosen = 0;
            for (int bin = 255; bin >= 0; --bin) {
                const unsigned c = hist[bin];
                if (acc + c >= remk) { chosen = bin; break; }
                acc += c;
            }
            s_cntgt += acc;
            s_remk = remk - acc;
            s_prefix = prefix | ((unsigned)chosen << shift);
        }
        __syncthreads();
    }

    const unsigned Tbits = s_prefix;
    const float T = __uint_as_float(Tbits);
    const unsigned cnt_gt = s_cntgt;
    const unsigned sel_eq = s_remk;   // = k - cnt_gt (ties at T selected)

    float sgt = 0.f;
    for (int i = tid; i < P_; i += SBLK) {
        const float v = sm[i];
        if (v > T) sgt += v;
    }
    for (int off=32; off; off>>=1) { sgt += __shfl_down(sgt, off); sp += __shfl_down(sp, off); }
    if (lane == 0) { s_r1[wid] = sgt; s_r2[wid] = sp; }
    __syncthreads();
    if (tid == 0) {
        float a = 0.f, c = 0.f;
        for (int w = 0; w < SBLK/64; ++w) { a += s_r1[w]; c += s_r2[w]; }
        float neg_sum, mc;
        if (Tbits != 0u) { neg_sum = a + (float)sel_eq * T; mc = (float)(pos + (int)k); }
        else             { neg_sum = a;                     mc = (float)(pos + (int)cnt_gt); }
        atomicAdd(conf_sum, c + neg_sum);
        atomicAdd(mask_cnt, mc);
    }
}

// ---------------- Kernel 6: finalize ----------------
__global__ void finalize_kernel(const float* __restrict__ accums, float* __restrict__ out)
{
    out[0] = accums[0] / (float)B_;                 // loc_loss
    out[1] = accums[1] / accums[2] / (float)B_;     // conf_loss
}

extern "C" void kernel_launch(void* const* d_in, const int* in_sizes, int n_in,
                              void* d_out, int out_size, void* d_ws, size_t ws_size,
                              hipStream_t stream) {
    (void)in_sizes; (void)n_in; (void)out_size; (void)ws_size;
    const float* pred_loc  = (const float*)d_in[0];
    const float* pred_conf = (const float*)d_in[1];
    const float* priors    = (const float*)d_in[2];
    const float* tboxes    = (const float*)d_in[3];
    const int*   tlabels   = (const int*)d_in[4];
    float* out = (float*)d_out;

    char* ws = (char*)d_ws;
    int*   tclass  = (int*)ws;                               // BP ints
    float* ce      = (float*)(ws + (size_t)BP_ * 4);         // BP floats
    int*   truth   = (int*)(ws + (size_t)BP_ * 8);           // BP ints
    unsigned long long* bestkey = (unsigned long long*)(ws + (size_t)BP_ * 12);  // B*M u64
    float* accums  = (float*)(ws + (size_t)BP_ * 12 + B_*M_*8);  // [loc,conf,maskcnt]

    init_kernel<<<1, 256, 0, stream>>>(bestkey, accums);
    iou_kernel<<<dim3(9, B_), 256, 0, stream>>>(priors, tboxes, truth, bestkey);
    override_kernel<<<1, B_, 0, stream>>>(bestkey, truth);
    loc_kernel<<<(BP_ + 1023) / 1024, 256, 0, stream>>>(pred_loc, priors, tboxes, tlabels,
                                                        truth, tclass, &accums[0]);
    ce_kernel<<<BP_ / CEB, 256, 0, stream>>>(pred_conf, tclass, ce);
    select_kernel<<<B_, SBLK, 0, stream>>>(ce, tclass, &accums[1], &accums[2]);
    finalize_kernel<<<1, 1, 0, stream>>>(accums, out);
}